// Round 1
// baseline (11370.293 us; speedup 1.0000x reference)
//
#include <hip/hip_runtime.h>
#include <hip/hip_bf16.h>

#define B_   64
#define T_   1024
#define IND_ 256
#define U_   512
#define G3_  1536
#define NWG  32

typedef unsigned int u32;
typedef unsigned long long u64;
typedef __attribute__((ext_vector_type(8))) short short8;
typedef __attribute__((ext_vector_type(4))) float f32x4;

union S8 { short8 v; unsigned short us[8]; u64 q[2]; };
union BF { __hip_bfloat16 b; unsigned short u; };

__device__ __forceinline__ unsigned short f2b(float f) {
  BF t; t.b = __float2bfloat16(f); return t.u;
}

__device__ __forceinline__ float hsig(float a) {
  return fminf(fmaxf(fmaf(a, 0.2f, 0.5f), 0.0f), 1.0f);
}

// ---------------- prep kernels ----------------

__global__ void k_zero(u32* c) { if (threadIdx.x == 0) *c = 0u; }

// transpose+convert recurrent_kernel [512][1536] -> WrT bf16 [1536][512]
// and kernel [256][1536] -> WxT bf16 [1536][256]
__global__ void k_wt(const float* __restrict__ rk, const float* __restrict__ xk,
                     unsigned short* __restrict__ WrT, unsigned short* __restrict__ WxT) {
  int i = blockIdx.x * 256 + threadIdx.x;
  if (i < U_ * G3_) {
    int k = i / G3_, c = i - k * G3_;
    WrT[(size_t)c * U_ + k] = f2b(rk[i]);
  } else {
    int j = i - U_ * G3_;
    int k = j / G3_, c = j - k * G3_;
    WxT[(size_t)c * IND_ + k] = f2b(xk[j]);
  }
}

// pp[b][c] = sum_k peak[b][k] * peak_kernel[k][c]   (fp32)
__global__ void k_pp(const float* __restrict__ peak, const float* __restrict__ pk,
                     float* __restrict__ pp) {
  int i = blockIdx.x * 256 + threadIdx.x;   // 64*1536 threads
  int b = i / G3_, c = i - b * G3_;
  const float* pr = peak + b * U_;
  float s = 0.f;
  for (int k = 0; k < U_; ++k) s = fmaf(pr[k], pk[(size_t)k * G3_ + c], s);
  pp[i] = s;
}

// h0[b][u] = sum_k peak[b][k] * peak_initial[k][u]; also write bf16 copy into hbuf[0]
__global__ void k_h0(const float* __restrict__ peak, const float* __restrict__ pi,
                     float* __restrict__ h0, unsigned short* __restrict__ hbuf) {
  int i = blockIdx.x * 256 + threadIdx.x;   // 64*512 threads
  int b = i >> 9, u = i & 511;
  const float* pr = peak + b * U_;
  float s = 0.f;
  for (int k = 0; k < U_; ++k) s = fmaf(pr[k], pi[(size_t)k * U_ + u], s);
  h0[i] = s;
  hbuf[i] = f2b(s);
}

// ---------------- scan kernel helpers ----------------

// x-GEMM contribution for one timestep: A = x[b, t, :] (f32 -> bf16), B = WxT (global)
__device__ __forceinline__ void gemm_x(const float* __restrict__ xr,
    const unsigned short* __restrict__ WxT, int wg, int c, int kg,
    f32x4& az, f32x4& ar, f32x4& ah)
{
#pragma unroll
  for (int ks = 0; ks < 8; ++ks) {
    int kofs = ks * 32 + kg * 8;
    const float4* xp = (const float4*)(xr + kofs);
    float4 x0 = xp[0], x1 = xp[1];
    S8 a;
    a.us[0] = f2b(x0.x); a.us[1] = f2b(x0.y); a.us[2] = f2b(x0.z); a.us[3] = f2b(x0.w);
    a.us[4] = f2b(x1.x); a.us[5] = f2b(x1.y); a.us[6] = f2b(x1.z); a.us[7] = f2b(x1.w);
    const unsigned short* wb = WxT + (size_t)(wg * 16 + c) * IND_ + kofs;
    short8 b0 = *(const short8*)(wb);
    short8 b1 = *(const short8*)(wb + (size_t)U_ * IND_);
    short8 b2 = *(const short8*)(wb + (size_t)2 * U_ * IND_);
    az = __builtin_amdgcn_mfma_f32_16x16x32_bf16(a.v, b0, az, 0, 0, 0);
    ar = __builtin_amdgcn_mfma_f32_16x16x32_bf16(a.v, b1, ar, 0, 0, 0);
    ah = __builtin_amdgcn_mfma_f32_16x16x32_bf16(a.v, b2, ah, 0, 0, 0);
  }
}

// ---------------- scan kernel ----------------
// 32 WGs x 256 threads. WG wg owns h-columns [wg*16, wg*16+16).
// LDS: Wr slice (48 cols x 512 k, bf16, XOR-swizzled) + folded bias/pp.

__global__ __launch_bounds__(256, 1) void k_scan(
    const float* __restrict__ x, const float* __restrict__ bias,
    const float* __restrict__ pp, const float* __restrict__ h0,
    const unsigned short* __restrict__ WrT, const unsigned short* __restrict__ WxT,
    unsigned short* __restrict__ hbuf, u32* __restrict__ counter,
    float* __restrict__ out)
{
  __shared__ short8 lWr[3072];             // 48 rows * 64 chunks of 8 bf16 (49152 B)
  __shared__ float lbpz[64 * 16], lbpr[64 * 16], lpph[64 * 16], lbh[16];

  const int wg = blockIdx.x;
  const int tid = threadIdx.x;
  const int lane = tid & 63;
  const int w = tid >> 6;        // wave id == m-tile (rows w*16 .. w*16+15)
  const int c = lane & 15;
  const int kg = lane >> 4;

  // stage Wr slice: rows = (gate g, col cc) -> WrT[g*512 + wg*16 + cc][k]
  for (int i = tid; i < 3072; i += 256) {
    int row = i >> 6;            // 0..47  (= g*16 + cc)
    int kb = (i & 63) << 3;      // k base
    int g = row >> 4, cc = row & 15;
    short8 v = *(const short8*)(WrT + (size_t)(g * U_ + wg * 16 + cc) * U_ + kb);
    lWr[i ^ (cc & 7)] = v;       // XOR swizzle on 16B-chunk index
  }
  // fold bias (+pp for z,r) into LDS
  for (int i = tid; i < 64 * 16; i += 256) {
    int b = i >> 4, cc = i & 15;
    int j = wg * 16 + cc;
    lbpz[i] = bias[j] + pp[(size_t)b * G3_ + j];
    lbpr[i] = bias[U_ + j] + pp[(size_t)b * G3_ + U_ + j];
    lpph[i] = pp[(size_t)b * G3_ + 2 * U_ + j];
  }
  if (tid < 16) lbh[tid] = bias[2 * U_ + wg * 16 + tid];

  const int arow = w * 16 + c;        // A-fragment row (batch index)
  const int erow0 = w * 16 + kg * 4;  // epilogue row base (C layout)
  const int j = wg * 16 + c;

  float hprev[4];
#pragma unroll
  for (int q = 0; q < 4; ++q) hprev[q] = h0[(size_t)(erow0 + q) * U_ + j];

  __syncthreads();

  const float* xr = x + (size_t)arow * (T_ * IND_);
  const f32x4 z4 = {0.f, 0.f, 0.f, 0.f};
  f32x4 paz = z4, par = z4, pah = z4;
  gemm_x(xr, WxT, wg, c, kg, paz, par, pah);   // prefetch t=0

  for (int t = 0; t < T_; ++t) {
    f32x4 az = paz, ar = par, ahx = pah, ahr = z4;

    // recurrent GEMM: A = h_t (bf16, device-coherent loads), B = Wr slice (LDS)
    const unsigned short* hb = hbuf + (size_t)(t & 1) * (B_ * U_) + (size_t)arow * U_;
#pragma unroll
    for (int ks = 0; ks < 16; ++ks) {
      int kofs = ks * 32 + kg * 8;
      S8 a;
      const u64* p = (const u64*)(hb + kofs);
      a.q[0] = __hip_atomic_load(p,     __ATOMIC_RELAXED, __HIP_MEMORY_SCOPE_AGENT);
      a.q[1] = __hip_atomic_load(p + 1, __ATOMIC_RELAXED, __HIP_MEMORY_SCOPE_AGENT);
      int kc = kofs >> 3;
      short8 bz = lWr[((0 * 16 + c) * 64 + kc) ^ (c & 7)];
      short8 br = lWr[((1 * 16 + c) * 64 + kc) ^ (c & 7)];
      short8 bh = lWr[((2 * 16 + c) * 64 + kc) ^ (c & 7)];
      az  = __builtin_amdgcn_mfma_f32_16x16x32_bf16(a.v, bz, az,  0, 0, 0);
      ar  = __builtin_amdgcn_mfma_f32_16x16x32_bf16(a.v, br, ar,  0, 0, 0);
      ahr = __builtin_amdgcn_mfma_f32_16x16x32_bf16(a.v, bh, ahr, 0, 0, 0);
    }

    // elementwise gates + state update (h carried in registers, fp32)
    unsigned short* ho = hbuf + (size_t)((t + 1) & 1) * (B_ * U_);
#pragma unroll
    for (int q = 0; q < 4; ++q) {
      int b = erow0 + q;
      int li = b * 16 + c;
      float z = hsig(az[q] + lbpz[li]);
      float r = hsig(ar[q] + lbpr[li]);
      float hh = tanhf(ahx[q] + lbh[c] + r * (ahr[q] + lpph[li]));
      float hn = fmaf(z, hprev[q] - hh, hh);   // z*h + (1-z)*hh
      hprev[q] = hn;
      out[((size_t)b * T_ + t) * U_ + j] = hn;
      // publish bf16 h (pack lane pairs -> 4B device-scope store)
      u32 hv = (u32)f2b(hn);
      u32 ov = (u32)__shfl_xor(hv, 1);
      if (!(lane & 1)) {
        u32 word = hv | (ov << 16);
        __hip_atomic_store((u32*)(ho + (size_t)b * U_ + j), word,
                           __ATOMIC_RELAXED, __HIP_MEMORY_SCOPE_AGENT);
      }
    }

    if (t < T_ - 1) {
      asm volatile("s_waitcnt vmcnt(0)" ::: "memory");   // drain sc1 h stores
      __syncthreads();
      if (tid == 0)
        __hip_atomic_fetch_add(counter, 1u, __ATOMIC_RELAXED, __HIP_MEMORY_SCOPE_AGENT);
      // hide part of barrier latency: prefetch next step's x-GEMM (h-independent)
      paz = z4; par = z4; pah = z4;
      gemm_x(xr + (size_t)(t + 1) * IND_, WxT, wg, c, kg, paz, par, pah);
      if (tid == 0) {
        u32 target = (u32)NWG * (u32)(t + 1);
        while (__hip_atomic_load(counter, __ATOMIC_RELAXED, __HIP_MEMORY_SCOPE_AGENT) < target)
          __builtin_amdgcn_s_sleep(2);
      }
      __syncthreads();
    }
  }
}

// ---------------- launch ----------------

extern "C" void kernel_launch(void* const* d_in, const int* in_sizes, int n_in,
                              void* d_out, int out_size, void* d_ws, size_t ws_size,
                              hipStream_t stream) {
  const float* x    = (const float*)d_in[0];
  const float* peak = (const float*)d_in[1];
  const float* xk   = (const float*)d_in[2];
  const float* rk   = (const float*)d_in[3];
  const float* pk   = (const float*)d_in[4];
  const float* bias = (const float*)d_in[5];
  const float* pi   = (const float*)d_in[6];
  float* out = (float*)d_out;

  char* w = (char*)d_ws;
  unsigned short* WrT  = (unsigned short*)(w);             // 1,572,864 B
  unsigned short* WxT  = (unsigned short*)(w + 1572864);   //   786,432 B
  float* pp            = (float*)(w + 2359296);            //   393,216 B
  float* h0            = (float*)(w + 2752512);            //   131,072 B
  unsigned short* hbuf = (unsigned short*)(w + 2883584);   //   131,072 B (2 buffers)
  u32* counter         = (u32*)(w + 3014656);              //       256 B

  k_zero<<<dim3(1), dim3(64), 0, stream>>>(counter);
  k_wt<<<dim3(4608), dim3(256), 0, stream>>>(rk, xk, WrT, WxT);
  k_pp<<<dim3(384), dim3(256), 0, stream>>>(peak, pk, pp);
  k_h0<<<dim3(128), dim3(256), 0, stream>>>(peak, pi, h0, hbuf);
  k_scan<<<dim3(NWG), dim3(256), 0, stream>>>(x, bias, pp, h0, WrT, WxT, hbuf, counter, out);
}

// Round 3
// 3821.369 us; speedup vs baseline: 2.9754x; 2.9754x over previous
//
#include <hip/hip_runtime.h>
#include <hip/hip_bf16.h>

#define B_   64
#define T_   1024
#define IND_ 256
#define U_   512
#define G3_  1536
#define NGRP  8     // batch groups (one per XCD under bid%8 round-robin)
#define BPG   8     // batches per group
#define SLOTS 32    // WGs per group; slot owns 16 h-columns

typedef unsigned int u32;
typedef unsigned short u16;
typedef unsigned long long u64;
typedef __attribute__((ext_vector_type(8))) short short8;
typedef __attribute__((ext_vector_type(4))) float f32x4;

union S8 { short8 v; u16 us[8]; u64 q[2]; };
union BF { __hip_bfloat16 b; u16 u; };

__device__ __forceinline__ u16 f2b(float f){ BF t; t.b = __float2bfloat16(f); return t.u; }
__device__ __forceinline__ float hsig(float a){ return fminf(fmaxf(fmaf(a, 0.2f, 0.5f), 0.f), 1.f); }

__device__ __forceinline__ void drain_vm(){
  asm volatile("s_waitcnt vmcnt(0)" ::: "memory");
  __builtin_amdgcn_sched_barrier(0);
}

// batched A-fragment load: 16 x 16B, device-coherent (sc0 sc1), ONE wait
#define LDA16(aa, hb) \
  asm volatile( \
    "global_load_dwordx4 %0,  %16, off sc0 sc1\n\t" \
    "global_load_dwordx4 %1,  %16, off offset:64 sc0 sc1\n\t" \
    "global_load_dwordx4 %2,  %16, off offset:128 sc0 sc1\n\t" \
    "global_load_dwordx4 %3,  %16, off offset:192 sc0 sc1\n\t" \
    "global_load_dwordx4 %4,  %16, off offset:256 sc0 sc1\n\t" \
    "global_load_dwordx4 %5,  %16, off offset:320 sc0 sc1\n\t" \
    "global_load_dwordx4 %6,  %16, off offset:384 sc0 sc1\n\t" \
    "global_load_dwordx4 %7,  %16, off offset:448 sc0 sc1\n\t" \
    "global_load_dwordx4 %8,  %16, off offset:512 sc0 sc1\n\t" \
    "global_load_dwordx4 %9,  %16, off offset:576 sc0 sc1\n\t" \
    "global_load_dwordx4 %10, %16, off offset:640 sc0 sc1\n\t" \
    "global_load_dwordx4 %11, %16, off offset:704 sc0 sc1\n\t" \
    "global_load_dwordx4 %12, %16, off offset:768 sc0 sc1\n\t" \
    "global_load_dwordx4 %13, %16, off offset:832 sc0 sc1\n\t" \
    "global_load_dwordx4 %14, %16, off offset:896 sc0 sc1\n\t" \
    "global_load_dwordx4 %15, %16, off offset:960 sc0 sc1\n\t" \
    "s_waitcnt vmcnt(0)" \
    : "=&v"(aa[0].v),  "=&v"(aa[1].v),  "=&v"(aa[2].v),  "=&v"(aa[3].v), \
      "=&v"(aa[4].v),  "=&v"(aa[5].v),  "=&v"(aa[6].v),  "=&v"(aa[7].v), \
      "=&v"(aa[8].v),  "=&v"(aa[9].v),  "=&v"(aa[10].v), "=&v"(aa[11].v), \
      "=&v"(aa[12].v), "=&v"(aa[13].v), "=&v"(aa[14].v), "=&v"(aa[15].v) \
    : "v"(hb) : "memory")

// ---------------- prep kernels ----------------

__global__ void k_zero(u32* c) {
  int i = blockIdx.x * 256 + threadIdx.x;
  if (i < 256) c[i] = 0u;
}

__global__ void k_wt(const float* __restrict__ rk, const float* __restrict__ xk,
                     u16* __restrict__ WrT, u16* __restrict__ WxT) {
  int i = blockIdx.x * 256 + threadIdx.x;
  if (i < U_ * G3_) {
    int k = i / G3_, c = i - k * G3_;
    WrT[(size_t)c * U_ + k] = f2b(rk[i]);
  } else {
    int j = i - U_ * G3_;
    int k = j / G3_, c = j - k * G3_;
    WxT[(size_t)c * IND_ + k] = f2b(xk[j]);
  }
}

__global__ void k_pp(const float* __restrict__ peak, const float* __restrict__ pk,
                     float* __restrict__ pp) {
  int i = blockIdx.x * 256 + threadIdx.x;   // 64*1536
  int b = i / G3_, c = i - b * G3_;
  const float* pr = peak + b * U_;
  float s = 0.f;
  for (int k = 0; k < U_; ++k) s = fmaf(pr[k], pk[(size_t)k * G3_ + c], s);
  pp[i] = s;
}

__global__ void k_h0(const float* __restrict__ peak, const float* __restrict__ pi,
                     float* __restrict__ h0) {
  int i = blockIdx.x * 256 + threadIdx.x;   // 64*512
  int b = i >> 9, u = i & 511;
  const float* pr = peak + b * U_;
  float s = 0.f;
  for (int k = 0; k < U_; ++k) s = fmaf(pr[k], pi[(size_t)k * U_ + u], s);
  h0[i] = s;
}

// ---------------- scan kernel ----------------
// 256 one-wave WGs. Group g = bid&7 owns batches [8g,8g+8); slot s = bid>>3
// owns h-columns [16s,16s+16). All sync device-scope (AGENT) -> hang-proof.

__global__ __launch_bounds__(64, 1) void k_scan(
    const float* __restrict__ x, const float* __restrict__ bias,
    const float* __restrict__ pp, const float* __restrict__ h0,
    const u16* __restrict__ WrT, const u16* __restrict__ WxT,
    u16* __restrict__ hbuf, u32* __restrict__ cnt, float* __restrict__ out)
{
  __shared__ short8 lB[4608];   // [0,3072): Wr frag-linear; [3072,4608): Wx. 72 KiB

  const int tid = threadIdx.x;
  const int g = blockIdx.x & 7;
  const int s = blockIdx.x >> 3;
  const int scol0 = s * 16;

  // stage Wr: LDS chunk (gate*16+ks)*64+lane <- WrT[gate*512+scol0+(lane&15)][ks*32+(lane>>4)*8..]
  for (int lin = tid; lin < 3072; lin += 64) {
    int lp = lin & 63, ks = (lin >> 6) & 15, gate = lin >> 10;
    int cc = lp & 15, kk = lp >> 4;
    lB[lin] = *(const short8*)(WrT + (size_t)(gate * U_ + scol0 + cc) * U_ + ks * 32 + kk * 8);
  }
  // stage Wx (K=256 -> 8 ks)
  for (int lin = tid; lin < 1536; lin += 64) {
    int lp = lin & 63, ks = (lin >> 6) & 7, gate = lin >> 9;
    int cc = lp & 15, kk = lp >> 4;
    lB[3072 + lin] = *(const short8*)(WxT + (size_t)(gate * U_ + scol0 + cc) * IND_ + ks * 32 + kk * 8);
  }
  __syncthreads();

  const int c   = tid & 15;
  const int kg  = tid >> 4;
  const int col = scol0 + c;
  const int kge = kg & 1;

  // per-lane epilogue tables in registers
  float bpz[4], bpr[4], pph[4], hprev[4];
  float bh = bias[2 * U_ + col];
#pragma unroll
  for (int q = 0; q < 4; ++q) {
    int bg = g * BPG + kge * 4 + q;
    bpz[q]   = bias[col]       + pp[(size_t)bg * G3_ + col];
    bpr[q]   = bias[U_ + col]  + pp[(size_t)bg * G3_ + U_ + col];
    pph[q]   = pp[(size_t)bg * G3_ + 2 * U_ + col];
    hprev[q] = h0[(size_t)bg * U_ + col];
  }

  u16* hbA = hbuf + (size_t)(g * 2 + 0) * BPG * U_;   // parity 0
  u16* hbB = hbuf + (size_t)(g * 2 + 1) * BPG * U_;   // parity 1
  u32* cntp = cnt + g * 32;                           // group counters, 128 B apart

  // publish h0 (parity 0), drain, arrive
#pragma unroll
  for (int q = 0; q < 4; ++q) {
    u32 hv = (u32)f2b(hprev[q]);
    u32 ov = (u32)__shfl_xor((int)hv, 1);
    if (kg < 2 && !(c & 1))
      __hip_atomic_store((u32*)(hbA + (size_t)(kg * 4 + q) * U_ + col), hv | (ov << 16),
                         __ATOMIC_RELAXED, __HIP_MEMORY_SCOPE_AGENT);
  }
  drain_vm();
  if (tid == 0)
    __hip_atomic_fetch_add(cntp, 1u, __ATOMIC_RELAXED, __HIP_MEMORY_SCOPE_AGENT);

  // x-GEMM for one timestep (A from global x fp32->bf16, B from LDS Wx)
  const float* xrow = x + (size_t)(g * BPG + (c & 7)) * T_ * IND_;
  const f32x4 z4 = {0.f, 0.f, 0.f, 0.f};
  f32x4 pxz = z4, pxr = z4, pxh = z4;

#define GEMM_X(tt, AZ, AR, AH) do { \
    const float* xp_ = xrow + (size_t)(tt) * IND_ + kg * 8; \
    _Pragma("unroll") \
    for (int ks = 0; ks < 8; ++ks) { \
      const float4* p4_ = (const float4*)(xp_ + ks * 32); \
      float4 x0_ = p4_[0], x1_ = p4_[1]; \
      S8 a_; \
      a_.us[0]=f2b(x0_.x); a_.us[1]=f2b(x0_.y); a_.us[2]=f2b(x0_.z); a_.us[3]=f2b(x0_.w); \
      a_.us[4]=f2b(x1_.x); a_.us[5]=f2b(x1_.y); a_.us[6]=f2b(x1_.z); a_.us[7]=f2b(x1_.w); \
      AZ = __builtin_amdgcn_mfma_f32_16x16x32_bf16(a_.v, lB[3072 + (0*8+ks)*64 + tid], AZ, 0,0,0); \
      AR = __builtin_amdgcn_mfma_f32_16x16x32_bf16(a_.v, lB[3072 + (1*8+ks)*64 + tid], AR, 0,0,0); \
      AH = __builtin_amdgcn_mfma_f32_16x16x32_bf16(a_.v, lB[3072 + (2*8+ks)*64 + tid], AH, 0,0,0); \
    } \
  } while (0)

  GEMM_X(0, pxz, pxr, pxh);   // prefetch t=0 between arrive and wait

  while (__hip_atomic_load(cntp, __ATOMIC_RELAXED, __HIP_MEMORY_SCOPE_AGENT) < (u32)SLOTS)
    __builtin_amdgcn_s_sleep(1);

  for (int t = 0; t < T_; ++t) {
    // load A fragments (h_t, bf16) — one pipelined batch, one wait
    const u16* hb = ((t & 1) ? hbB : hbA) + (size_t)(c & 7) * U_ + kg * 8;
    S8 aa[16];
    LDA16(aa, hb);

    f32x4 az = pxz, ar = pxr, ah = pxh, ahr = z4;
#pragma unroll
    for (int ks = 0; ks < 16; ++ks) {
      az  = __builtin_amdgcn_mfma_f32_16x16x32_bf16(aa[ks].v, lB[(0*16+ks)*64 + tid], az,  0,0,0);
      ar  = __builtin_amdgcn_mfma_f32_16x16x32_bf16(aa[ks].v, lB[(1*16+ks)*64 + tid], ar,  0,0,0);
      ahr = __builtin_amdgcn_mfma_f32_16x16x32_bf16(aa[ks].v, lB[(2*16+ks)*64 + tid], ahr, 0,0,0);
    }

    // gates + state update (fp32, h carried in registers)
    float hnew[4];
#pragma unroll
    for (int q = 0; q < 4; ++q) {
      float z  = hsig(az[q] + bpz[q]);
      float r  = hsig(ar[q] + bpr[q]);
      float hh = tanhf(ah[q] + bh + r * (ahr[q] + pph[q]));
      hnew[q] = fmaf(z, hprev[q] - hh, hh);
      hprev[q] = hnew[q];
    }

    // publish h_{t+1} (bf16 packed pairs, device-scope), drain, arrive
    u16* ho = (t & 1) ? hbA : hbB;
#pragma unroll
    for (int q = 0; q < 4; ++q) {
      u32 hv = (u32)f2b(hnew[q]);
      u32 ov = (u32)__shfl_xor((int)hv, 1);
      if (kg < 2 && !(c & 1))
        __hip_atomic_store((u32*)(ho + (size_t)(kg * 4 + q) * U_ + col), hv | (ov << 16),
                           __ATOMIC_RELAXED, __HIP_MEMORY_SCOPE_AGENT);
    }
    drain_vm();
    if (tid == 0)
      __hip_atomic_fetch_add(cntp, 1u, __ATOMIC_RELAXED, __HIP_MEMORY_SCOPE_AGENT);

    // wait window: out stores + next x-GEMM (h-independent)
    if (kg < 2) {
#pragma unroll
      for (int q = 0; q < 4; ++q) {
        int bg = g * BPG + kg * 4 + q;
        out[((size_t)bg * T_ + t) * U_ + col] = hnew[q];
      }
    }
    if (t < T_ - 1) {
      pxz = z4; pxr = z4; pxh = z4;
      GEMM_X(t + 1, pxz, pxr, pxh);
      u32 target = (u32)SLOTS * (u32)(t + 2);
      while (__hip_atomic_load(cntp, __ATOMIC_RELAXED, __HIP_MEMORY_SCOPE_AGENT) < target)
        __builtin_amdgcn_s_sleep(1);
    }
  }
}

// ---------------- launch ----------------

extern "C" void kernel_launch(void* const* d_in, const int* in_sizes, int n_in,
                              void* d_out, int out_size, void* d_ws, size_t ws_size,
                              hipStream_t stream) {
  const float* x    = (const float*)d_in[0];
  const float* peak = (const float*)d_in[1];
  const float* xk   = (const float*)d_in[2];
  const float* rk   = (const float*)d_in[3];
  const float* pk   = (const float*)d_in[4];
  const float* bias = (const float*)d_in[5];
  const float* pi   = (const float*)d_in[6];
  float* out = (float*)d_out;

  char* w = (char*)d_ws;
  u16*   WrT  = (u16*)(w);               // 1,572,864 B  [1536][512] bf16
  u16*   WxT  = (u16*)(w + 1572864);     //   786,432 B  [1536][256] bf16
  float* pp   = (float*)(w + 2359296);   //   393,216 B
  float* h0   = (float*)(w + 2752512);   //   131,072 B
  u16*   hbuf = (u16*)(w + 2883584);     //   131,072 B  [8 groups][2][8][512] bf16
  u32*   cnt  = (u32*)(w + 3014656);     //     1,024 B  per-group step counters

  k_zero<<<dim3(1),    dim3(256), 0, stream>>>(cnt);
  k_wt  <<<dim3(4608), dim3(256), 0, stream>>>(rk, xk, WrT, WxT);
  k_pp  <<<dim3(384),  dim3(256), 0, stream>>>(peak, pk, pp);
  k_h0  <<<dim3(128),  dim3(256), 0, stream>>>(peak, pi, h0);
  k_scan<<<dim3(256),  dim3(64),  0, stream>>>(x, bias, pp, h0, WrT, WxT, hbuf, cnt, out);
}